// Round 2
// baseline (1002.481 us; speedup 1.0000x reference)
//
#include <hip/hip_runtime.h>
#include <cstdint>
#include <cstddef>

#define NB 64
#define NP 24564
#define NC 81
#define NROWS (NB*NP)   // 1,572,096
#define NT 50
#define TCH 10          // truths per block in best-prior kernel
#define NSEG 16         // P-segments in best-prior kernel
#define SEGLEN 1536     // 16*1536 = 24576 >= NP
#define RPB 64          // rows per k_ce block (4 threads/row, 256 threads)

__device__ __forceinline__ unsigned long long umax64(unsigned long long a, unsigned long long b){
  return a > b ? a : b;
}

// ---------------------------------------------------------------------------
// Kernel A: per (b,t) best prior (argmax over P), P split into NSEG segments.
// packed u64 key = (iou_bits<<32) | ~p  -> max = (max iou, then smallest p).
// Wave shuffle reduce -> 4 partials in LDS -> global atomicMax into bpk.
// ---------------------------------------------------------------------------
__global__ __launch_bounds__(256) void k_bestprior(
    const float* __restrict__ priors, const float* __restrict__ tboxes,
    unsigned long long* __restrict__ bpk)
{
  __shared__ float tb[TCH*4];
  __shared__ float ta[TCH];
  __shared__ unsigned long long part[4][TCH];
  const int tid = threadIdx.x;
  const int b  = blockIdx.x;
  const int t0 = blockIdx.y * TCH;
  const int i0 = blockIdx.z * SEGLEN;
  const int iend = min(i0 + SEGLEN, NP);
  if (tid < TCH*4) tb[tid] = tboxes[(b*NT + t0)*4 + tid];
  __syncthreads();
  if (tid < TCH) ta[tid] = (tb[tid*4+2]-tb[tid*4+0]) * (tb[tid*4+3]-tb[tid*4+1]);
  __syncthreads();

  unsigned long long best[TCH];
  #pragma unroll
  for (int j = 0; j < TCH; ++j) best[j] = 0ULL;

  for (int i = i0 + tid; i < iend; i += 256){
    const float4 pr = ((const float4* __restrict__)priors)[i];
    const float px1 = pr.x - 0.5f*pr.z, py1 = pr.y - 0.5f*pr.w;
    const float px2 = pr.x + 0.5f*pr.z, py2 = pr.y + 0.5f*pr.w;
    const float pa  = pr.z * pr.w;
    const unsigned long long low = (unsigned long long)(~(unsigned)i);
    #pragma unroll
    for (int j = 0; j < TCH; ++j){
      float ix = fminf(tb[j*4+2], px2) - fmaxf(tb[j*4+0], px1);
      float iy = fminf(tb[j*4+3], py2) - fmaxf(tb[j*4+1], py1);
      ix = fmaxf(ix, 0.0f); iy = fmaxf(iy, 0.0f);
      const float inter = ix * iy;
      const float iou = inter / (ta[j] + pa - inter);
      const unsigned long long key =
          ((unsigned long long)__float_as_uint(iou) << 32) | low;
      best[j] = umax64(best[j], key);
    }
  }
  // wave-level reduce (64 lanes)
  #pragma unroll
  for (int off = 32; off > 0; off >>= 1){
    #pragma unroll
    for (int j = 0; j < TCH; ++j)
      best[j] = umax64(best[j], __shfl_down(best[j], off));
  }
  const int wv = tid >> 6;
  if ((tid & 63) == 0){
    #pragma unroll
    for (int j = 0; j < TCH; ++j) part[wv][j] = best[j];
  }
  __syncthreads();
  if (tid < TCH){
    const unsigned long long m =
        umax64(umax64(part[0][tid], part[1][tid]),
               umax64(part[2][tid], part[3][tid]));
    atomicMax(&bpk[b*NT + t0 + tid], m);
  }
}

// ---------------------------------------------------------------------------
// Kernel B: fused matching + CE + positive loc loss + counts.
// 256-thread block stages RPB=64 rows of conf into LDS (20.7 KB tile ->
// 5-7 blocks/CU) with UNROLLED two-phase staging: 6 independent float4
// loads into st[] (static indices -> registers), then 6 ds_writes. This
// restores the MLP the R1 runtime-bound staging loop lost (its per-iter
// load->vmcnt(0)->ds_write chain serialized 10 HBM round trips).
// 4 threads/row: q=0 cols[0,21), q=1 [21,41), q=2 [41,61), q=3 [61,81);
// max/sumexp combined via __shfl_xor 1,2. Matching duplicated x4 (~35us
// chip-wide VALU, hidden under the HBM stream). Single __syncthreads():
// truth metadata loaded by spare threads straight from global.
// ---------------------------------------------------------------------------
__global__ __launch_bounds__(256) void k_ce(
    const float* __restrict__ conf, const float* __restrict__ loc,
    const float* __restrict__ priors, const float* __restrict__ tboxes,
    const int* __restrict__ tlabels,
    const unsigned long long* __restrict__ bpk,
    float* __restrict__ mine, float* __restrict__ ce_pos,
    float* __restrict__ loss_l, int* __restrict__ num_pos)
{
  __shared__ float4 cbuf4[(RPB*NC)/4 + 1];   // 1296 float4 + 1 guard = 20,752 B
  __shared__ float4 tb4[NT];
  __shared__ float ta[NT];
  __shared__ int ips[NT];
  __shared__ int tl[NT];
  float* cbuf = (float*)cbuf4;

  const int tid = threadIdx.x;
  const int b  = blockIdx.y;
  const int p0 = blockIdx.x * RPB;
  const int rows = min(RPB, NP - p0);

  // --- phase 1: issue all staging loads (independent, in flight together) ---
  const float4* __restrict__ csrc =
      (const float4* __restrict__)(conf + (size_t)(b*NP + p0) * NC);
  const int nf4 = (rows * NC) >> 2;          // rows%4==0 always -> exact
  float4 st[6];
  #pragma unroll
  for (int j = 0; j < 6; ++j){
    const int i = tid + j*256;
    if (i < nf4) st[j] = csrc[i];
  }

  // --- truth metadata in parallel with the staging loads ---
  if (tid < NT*4){
    ((float*)tb4)[tid] = tboxes[b*NT*4 + tid];
  } else if (tid < NT*4 + NT){
    const int t = tid - NT*4;
    const float4 T = ((const float4* __restrict__)tboxes)[b*NT + t];
    ta[t] = (T.z - T.x) * (T.w - T.y);
    tl[t] = tlabels[b*NT + t];
    ips[t] = (int)(~(unsigned)(bpk[b*NT + t] & 0xffffffffULL));
  }

  // --- phase 2: write staged data to LDS ---
  #pragma unroll
  for (int j = 0; j < 6; ++j){
    const int i = tid + j*256;
    if (i < nf4) cbuf4[i] = st[j];
  }
  __syncthreads();

  const int row = tid >> 2;        // 0..63
  const int q   = tid & 3;         // quarter of the row
  const bool active = row < rows;
  const int p = p0 + (active ? row : 0);
  const int r = b*NP + p;

  // --- matching: best truth for this prior (duplicated across the quad) ---
  const float4 pr = ((const float4* __restrict__)priors)[p];
  const float px1 = pr.x - 0.5f*pr.z, py1 = pr.y - 0.5f*pr.w;
  const float px2 = pr.x + 0.5f*pr.z, py2 = pr.y + 0.5f*pr.w;
  const float pa  = pr.z * pr.w;
  float ov = -1.0f; int ti = 0;
  for (int t = 0; t < NT; ++t){
    const float4 T = tb4[t];                 // ds_read_b128
    float ix = fminf(T.z, px2) - fmaxf(T.x, px1);
    float iy = fminf(T.w, py2) - fmaxf(T.y, py1);
    ix = fmaxf(ix, 0.0f); iy = fmaxf(iy, 0.0f);
    const float inter = ix * iy;
    const float iou = inter / (ta[t] + pa - inter);
    if (iou > ov){ ov = iou; ti = t; }        // strict > = first occurrence
  }
  // --- best-prior override (ascending = last-write-wins) ---
  #pragma unroll 10
  for (int t = 0; t < NT; ++t){
    if (ips[t] == p){ ov = 2.0f; ti = t; }
  }
  const int cls = (ov < 0.5f) ? 0 : (tl[ti] + 1);

  // --- softmax CE: quarter-row from LDS into registers (static idx only) ---
  const float* __restrict__ myrow = cbuf + row * NC;
  const int c0 = q ? (1 + 20*q) : 0;         // 0,21,41,61
  const int cnt = q ? 20 : 21;
  float v[21];
  #pragma unroll
  for (int c = 0; c < 21; ++c)
    v[c] = (c < cnt) ? myrow[c0 + c] : -INFINITY;

  float mh = v[0];
  #pragma unroll
  for (int c = 1; c < 21; ++c) mh = fmaxf(mh, v[c]);
  float m = fmaxf(mh, __shfl_xor(mh, 1));
  m = fmaxf(m, __shfl_xor(m, 2));

  float sh = 0.0f;
  #pragma unroll
  for (int c = 0; c < 21; ++c) sh += __expf(v[c] - m);   // exp(-inf)=0 pads
  float S = sh + __shfl_xor(sh, 1);
  S += __shfl_xor(S, 2);

  const float lg = myrow[cls];               // broadcast within the quad
  const float ce = m + __logf(S) - lg;

  const bool own = active && (q == 0);
  const bool pos = own && (cls > 0);
  if (own) mine[r] = pos ? 0.0f : ce;

  float cp = pos ? ce : 0.0f;
  float ll = 0.0f;
  int   pc = pos ? 1 : 0;
  if (pos){
    const float4 T = tb4[ti];
    const float gcx = ((T.x + T.z)*0.5f - pr.x) / (0.1f*pr.z);
    const float gcy = ((T.y + T.w)*0.5f - pr.y) / (0.1f*pr.w);
    const float gw  = __logf((T.z - T.x) / pr.z) * 5.0f;
    const float gh  = __logf((T.w - T.y) / pr.w) * 5.0f;
    const float4 ld = ((const float4* __restrict__)loc)[r];
    float d, ad;
    d = ld.x - gcx; ad = fabsf(d); ll += (ad < 1.0f) ? 0.5f*d*d : ad - 0.5f;
    d = ld.y - gcy; ad = fabsf(d); ll += (ad < 1.0f) ? 0.5f*d*d : ad - 0.5f;
    d = ld.z - gw;  ad = fabsf(d); ll += (ad < 1.0f) ? 0.5f*d*d : ad - 0.5f;
    d = ld.w - gh;  ad = fabsf(d); ll += (ad < 1.0f) ? 0.5f*d*d : ad - 0.5f;
  }

  // wave -> block reduction, 3 atomics per block total
  #pragma unroll
  for (int off = 32; off > 0; off >>= 1){
    cp += __shfl_down(cp, off);
    ll += __shfl_down(ll, off);
    pc += __shfl_down(pc, off);
  }
  __shared__ float rcp[4], rll[4];
  __shared__ int rpc[4];
  const int wv = tid >> 6;
  if ((tid & 63) == 0){ rcp[wv] = cp; rll[wv] = ll; rpc[wv] = pc; }
  __syncthreads();
  if (tid == 0){
    atomicAdd(&ce_pos[b], (rcp[0]+rcp[1])+(rcp[2]+rcp[3]));
    atomicAdd(&loss_l[b], (rll[0]+rll[1])+(rll[2]+rll[3]));
    atomicAdd(&num_pos[b], (rpc[0]+rpc[1])+(rpc[2]+rpc[3]));
  }
}

// ---------------------------------------------------------------------------
// Kernel D: exact top-k sum per image via 4-pass radix select on float bits.
// 1024 threads; NP = 6141 float4 exactly; single-wave suffix scan (3 syncs
// per pass instead of 16).
// ---------------------------------------------------------------------------
__global__ __launch_bounds__(1024) void k_topk(
    const float* __restrict__ mine, const int* __restrict__ num_pos,
    float* __restrict__ topk)
{
  const int b = blockIdx.x;
  const int tid = threadIdx.x;
  const float4* __restrict__ d4 =
      (const float4* __restrict__)(mine + (size_t)b * NP);   // 6141 float4
  const int k = min(3 * num_pos[b], NP - 1);

  __shared__ unsigned hist[256];
  __shared__ unsigned s_prefix;
  __shared__ int s_rem;
  __shared__ float wsum[16];

  if (k <= 0){
    if (tid == 0) topk[b] = 0.0f;
    return;
  }
  if (tid == 0){ s_prefix = 0u; s_rem = k; }

  for (int pass = 0; pass < 4; ++pass){
    const int shift = 24 - pass*8;
    if (tid < 256) hist[tid] = 0u;
    __syncthreads();                          // (A) hist zeroed, sel stable
    const unsigned pref = s_prefix;
    const int rem = s_rem;
    for (int i = tid; i < 6141; i += 1024){
      const float4 v = d4[i];
      unsigned u;
      u = __float_as_uint(v.x);
      if (pass == 0 || (u >> (shift+8)) == pref) atomicAdd(&hist[(u>>shift)&255u], 1u);
      u = __float_as_uint(v.y);
      if (pass == 0 || (u >> (shift+8)) == pref) atomicAdd(&hist[(u>>shift)&255u], 1u);
      u = __float_as_uint(v.z);
      if (pass == 0 || (u >> (shift+8)) == pref) atomicAdd(&hist[(u>>shift)&255u], 1u);
      u = __float_as_uint(v.w);
      if (pass == 0 || (u >> (shift+8)) == pref) atomicAdd(&hist[(u>>shift)&255u], 1u);
    }
    __syncthreads();                          // (B) hist complete
    if (tid < 64){
      const unsigned h0 = hist[4*tid], h1 = hist[4*tid+1];
      const unsigned h2 = hist[4*tid+2], h3 = hist[4*tid+3];
      const unsigned pl = h0 + h1 + h2 + h3;
      unsigned S = pl;                        // inclusive suffix over lanes
      #pragma unroll
      for (int off = 1; off < 64; off <<= 1){
        const unsigned v = __shfl_down(S, off);
        if (tid + off < 64) S += v;
      }
      const unsigned Sn = S - pl;             // suffix starting at bin 4*tid+4
      const unsigned t3 = h3 + Sn;
      const unsigned t2 = h2 + t3;
      const unsigned t1 = h1 + t2;
      const unsigned t0 = h0 + t1;
      if ((int)t0 >= rem && (int)t1 < rem){ s_prefix = (pref<<8) | (4u*tid+0u); s_rem = rem - (int)t1; }
      if ((int)t1 >= rem && (int)t2 < rem){ s_prefix = (pref<<8) | (4u*tid+1u); s_rem = rem - (int)t2; }
      if ((int)t2 >= rem && (int)t3 < rem){ s_prefix = (pref<<8) | (4u*tid+2u); s_rem = rem - (int)t3; }
      if ((int)t3 >= rem && (int)Sn < rem){ s_prefix = (pref<<8) | (4u*tid+3u); s_rem = rem - (int)Sn; }
    }
    __syncthreads();                          // (C) selection visible
  }

  const unsigned kb = s_prefix;
  const int rem = s_rem;
  const float kv = __uint_as_float(kb);
  float acc = 0.0f;
  for (int i = tid; i < 6141; i += 1024){
    const float4 v = d4[i];
    if (__float_as_uint(v.x) > kb) acc += v.x;
    if (__float_as_uint(v.y) > kb) acc += v.y;
    if (__float_as_uint(v.z) > kb) acc += v.z;
    if (__float_as_uint(v.w) > kb) acc += v.w;
  }
  #pragma unroll
  for (int off = 32; off > 0; off >>= 1) acc += __shfl_down(acc, off);
  if ((tid & 63) == 0) wsum[tid >> 6] = acc;
  __syncthreads();
  if (tid == 0){
    float s = 0.0f;
    #pragma unroll
    for (int j = 0; j < 16; ++j) s += wsum[j];
    topk[b] = s + (float)rem * kv;
  }
}

// ---------------------------------------------------------------------------
// Kernel E: final combine
// ---------------------------------------------------------------------------
__global__ void k_final(const int* __restrict__ num_pos,
                        const float* __restrict__ loss_l,
                        const float* __restrict__ ce_pos,
                        const float* __restrict__ topk,
                        float* __restrict__ out)
{
  const int tid = threadIdx.x;
  int   np = num_pos[tid];
  float ll = loss_l[tid];
  float cp = ce_pos[tid];
  float tk = topk[tid];
  #pragma unroll
  for (int off = 32; off > 0; off >>= 1){
    np += __shfl_down(np, off);
    ll += __shfl_down(ll, off);
    cp += __shfl_down(cp, off);
    tk += __shfl_down(tk, off);
  }
  if (tid == 0){
    const float n = (float)max(np, 1);
    out[0] = ll / n;
    out[1] = (cp + tk) / n;
  }
}

// ---------------------------------------------------------------------------
extern "C" void kernel_launch(void* const* d_in, const int* in_sizes, int n_in,
                              void* d_out, int out_size, void* d_ws, size_t ws_size,
                              hipStream_t stream)
{
  const float* loc     = (const float*)d_in[0];
  const float* conf    = (const float*)d_in[1];
  const float* priors  = (const float*)d_in[2];
  const float* tboxes  = (const float*)d_in[3];
  const int*   tlabels = (const int*)d_in[4];
  float* out = (float*)d_out;

  char* ws = (char*)d_ws;
  int*   num_pos = (int*)(ws + 0);        // 64
  float* loss_l  = (float*)(ws + 256);    // 64
  float* ce_pos  = (float*)(ws + 512);    // 64
  float* topk    = (float*)(ws + 768);    // 64
  unsigned long long* bpk = (unsigned long long*)(ws + 1024);  // 64*50*8
  float* mine = (float*)(ws + 26624);     // NROWS floats, 16B aligned

  hipMemsetAsync(ws, 0, 26624, stream);

  dim3 gA(NB, NT/TCH, NSEG);
  k_bestprior<<<gA, 256, 0, stream>>>(priors, tboxes, bpk);

  dim3 gC((NP + RPB - 1)/RPB, NB);
  k_ce<<<gC, 256, 0, stream>>>(conf, loc, priors, tboxes, tlabels,
                               bpk, mine, ce_pos, loss_l, num_pos);

  k_topk<<<NB, 1024, 0, stream>>>(mine, num_pos, topk);

  k_final<<<1, 64, 0, stream>>>(num_pos, loss_l, ce_pos, topk, out);
}

// Round 3
// 977.683 us; speedup vs baseline: 1.0254x; 1.0254x over previous
//
#include <hip/hip_runtime.h>
#include <cstdint>
#include <cstddef>

#define NB 64
#define NP 24564
#define NC 81
#define NROWS (NB*NP)   // 1,572,096
#define NT 50
#define TCH 10          // truths per block in best-prior kernel
#define NSEG 16         // P-segments in best-prior kernel
#define SEGLEN 1536     // 16*1536 = 24576 >= NP
#define RPB 64          // rows per k_ce block (4 threads/row, 256 threads)

__device__ __forceinline__ unsigned long long umax64(unsigned long long a, unsigned long long b){
  return a > b ? a : b;
}

// ---------------------------------------------------------------------------
// Kernel A: per (b,t) best prior (argmax over P), P split into NSEG segments.
// packed u64 key = (iou_bits<<32) | ~p  -> max = (max iou, then smallest p).
// Wave shuffle reduce -> 4 partials in LDS -> global atomicMax into bpk.
// ---------------------------------------------------------------------------
__global__ __launch_bounds__(256) void k_bestprior(
    const float* __restrict__ priors, const float* __restrict__ tboxes,
    unsigned long long* __restrict__ bpk)
{
  __shared__ float tb[TCH*4];
  __shared__ float ta[TCH];
  __shared__ unsigned long long part[4][TCH];
  const int tid = threadIdx.x;
  const int b  = blockIdx.x;
  const int t0 = blockIdx.y * TCH;
  const int i0 = blockIdx.z * SEGLEN;
  const int iend = min(i0 + SEGLEN, NP);
  if (tid < TCH*4) tb[tid] = tboxes[(b*NT + t0)*4 + tid];
  __syncthreads();
  if (tid < TCH) ta[tid] = (tb[tid*4+2]-tb[tid*4+0]) * (tb[tid*4+3]-tb[tid*4+1]);
  __syncthreads();

  unsigned long long best[TCH];
  #pragma unroll
  for (int j = 0; j < TCH; ++j) best[j] = 0ULL;

  for (int i = i0 + tid; i < iend; i += 256){
    const float4 pr = ((const float4* __restrict__)priors)[i];
    const float px1 = pr.x - 0.5f*pr.z, py1 = pr.y - 0.5f*pr.w;
    const float px2 = pr.x + 0.5f*pr.z, py2 = pr.y + 0.5f*pr.w;
    const float pa  = pr.z * pr.w;
    const unsigned long long low = (unsigned long long)(~(unsigned)i);
    #pragma unroll
    for (int j = 0; j < TCH; ++j){
      float ix = fminf(tb[j*4+2], px2) - fmaxf(tb[j*4+0], px1);
      float iy = fminf(tb[j*4+3], py2) - fmaxf(tb[j*4+1], py1);
      ix = fmaxf(ix, 0.0f); iy = fmaxf(iy, 0.0f);
      const float inter = ix * iy;
      const float iou = inter / (ta[j] + pa - inter);
      const unsigned long long key =
          ((unsigned long long)__float_as_uint(iou) << 32) | low;
      best[j] = umax64(best[j], key);
    }
  }
  // wave-level reduce (64 lanes)
  #pragma unroll
  for (int off = 32; off > 0; off >>= 1){
    #pragma unroll
    for (int j = 0; j < TCH; ++j)
      best[j] = umax64(best[j], __shfl_down(best[j], off));
  }
  const int wv = tid >> 6;
  if ((tid & 63) == 0){
    #pragma unroll
    for (int j = 0; j < TCH; ++j) part[wv][j] = best[j];
  }
  __syncthreads();
  if (tid < TCH){
    const unsigned long long m =
        umax64(umax64(part[0][tid], part[1][tid]),
               umax64(part[2][tid], part[3][tid]));
    atomicMax(&bpk[b*NT + t0 + tid], m);
  }
}

// ---------------------------------------------------------------------------
// Kernel B: fused matching + CE + positive loc loss + counts.
// 256 threads stage RPB=64 conf rows to LDS (two-phase unrolled st[6]:
// all loads issued, then all ds_writes -> full MLP). 4 threads/row.
// R3 fixes vs R2 (counter-driven):
//  * NO per-thread float arrays (R2's v[21] spilled -> 518 MB scratch
//    writes, 82 B/thread): softmax is two LDS passes (max, then exp-sum).
//  * matching 50-truth loop split across the quad (13/thread) with packed
//    u64 key (iou_bits<<32)|~t reduced via shfl_xor(1,2) — same argmax +
//    first-occurrence tie-break; override reduced as max-t (last-write-wins).
//    Cuts the dominant VALU term (IoU with IEEE div) 4x.
// ---------------------------------------------------------------------------
__global__ __launch_bounds__(256) void k_ce(
    const float* __restrict__ conf, const float* __restrict__ loc,
    const float* __restrict__ priors, const float* __restrict__ tboxes,
    const int* __restrict__ tlabels,
    const unsigned long long* __restrict__ bpk,
    float* __restrict__ mine, float* __restrict__ ce_pos,
    float* __restrict__ loss_l, int* __restrict__ num_pos)
{
  __shared__ float4 cbuf4[(RPB*NC)/4 + 1];   // 1296 float4 + guard = 20,752 B
  __shared__ float4 tb4[NT];
  __shared__ float ta[NT];
  __shared__ int ips[NT];
  __shared__ int tl[NT];
  float* cbuf = (float*)cbuf4;

  const int tid = threadIdx.x;
  const int b  = blockIdx.y;
  const int p0 = blockIdx.x * RPB;
  const int rows = min(RPB, NP - p0);

  // --- phase 1: issue all staging loads (independent, in flight together) ---
  const float4* __restrict__ csrc =
      (const float4* __restrict__)(conf + (size_t)(b*NP + p0) * NC);
  const int nf4 = (rows * NC) >> 2;          // rows%4==0 always -> exact
  float4 st[6];
  #pragma unroll
  for (int j = 0; j < 6; ++j){
    const int i = tid + j*256;
    if (i < nf4) st[j] = csrc[i];
  }

  // --- truth metadata in parallel with the staging loads ---
  if (tid < NT*4){
    ((float*)tb4)[tid] = tboxes[b*NT*4 + tid];
  } else if (tid < NT*4 + NT){
    const int t = tid - NT*4;
    const float4 T = ((const float4* __restrict__)tboxes)[b*NT + t];
    ta[t] = (T.z - T.x) * (T.w - T.y);
    tl[t] = tlabels[b*NT + t];
    ips[t] = (int)(~(unsigned)(bpk[b*NT + t] & 0xffffffffULL));
  }

  // --- phase 2: write staged data to LDS ---
  #pragma unroll
  for (int j = 0; j < 6; ++j){
    const int i = tid + j*256;
    if (i < nf4) cbuf4[i] = st[j];
  }
  __syncthreads();

  const int row = tid >> 2;        // 0..63
  const int q   = tid & 3;         // quarter of the row
  const bool active = row < rows;
  const int p = p0 + (active ? row : 0);
  const int r = b*NP + p;

  // --- matching: 50 truths split across the quad (t = q, q+4, ...) ---
  const float4 pr = ((const float4* __restrict__)priors)[p];
  const float px1 = pr.x - 0.5f*pr.z, py1 = pr.y - 0.5f*pr.w;
  const float px2 = pr.x + 0.5f*pr.z, py2 = pr.y + 0.5f*pr.w;
  const float pa  = pr.z * pr.w;
  unsigned long long bk = 0ULL;
  int mo = -1;                      // override candidate (max t wins)
  {
    int t = q;
    #pragma unroll
    for (int k = 0; k < 13; ++k){
      if (t < NT){
        const float4 T = tb4[t];               // broadcast ds_read_b128
        float ix = fminf(T.z, px2) - fmaxf(T.x, px1);
        float iy = fminf(T.w, py2) - fmaxf(T.y, py1);
        ix = fmaxf(ix, 0.0f); iy = fmaxf(iy, 0.0f);
        const float inter = ix * iy;
        const float iou = inter / (ta[t] + pa - inter);   // iou >= 0
        const unsigned long long key =
            ((unsigned long long)__float_as_uint(iou) << 32)
            | (unsigned long long)(~(unsigned)t);
        bk = umax64(bk, key);
        if (ips[t] == p) mo = t;    // ascending within thread -> max kept
      }
      t += 4;
    }
  }
  bk = umax64(bk, __shfl_xor(bk, 1));
  bk = umax64(bk, __shfl_xor(bk, 2));
  mo = max(mo, __shfl_xor(mo, 1));
  mo = max(mo, __shfl_xor(mo, 2));
  int   ti = (int)(~(unsigned)(bk & 0xffffffffULL));
  float ov = __uint_as_float((unsigned)(bk >> 32));
  if (mo >= 0){ ov = 2.0f; ti = mo; }
  const int cls = (ov < 0.5f) ? 0 : (tl[ti] + 1);

  // --- softmax CE: two LDS passes over the quarter (no register array) ---
  // q covers cols [20q, 20q+20); q==3 additionally col 80.
  const float* __restrict__ myrow = cbuf + row * NC;
  const int c0 = 20 * q;
  const float x20 = (q == 3) ? myrow[80] : -INFINITY;

  float mh = myrow[c0];
  #pragma unroll
  for (int c = 1; c < 20; ++c) mh = fmaxf(mh, myrow[c0 + c]);
  mh = fmaxf(mh, x20);
  float m = fmaxf(mh, __shfl_xor(mh, 1));
  m = fmaxf(m, __shfl_xor(m, 2));

  float sh = 0.0f;
  #pragma unroll
  for (int c = 0; c < 20; ++c) sh += __expf(myrow[c0 + c] - m);
  sh += __expf(x20 - m);            // exp(-inf)=0 for q!=3
  float S = sh + __shfl_xor(sh, 1);
  S += __shfl_xor(S, 2);

  const float lg = myrow[cls];      // broadcast within the quad
  const float ce = m + __logf(S) - lg;

  const bool own = active && (q == 0);
  const bool pos = own && (cls > 0);
  if (own) mine[r] = pos ? 0.0f : ce;

  float cp = pos ? ce : 0.0f;
  float ll = 0.0f;
  int   pc = pos ? 1 : 0;
  if (pos){
    const float4 T = tb4[ti];
    const float gcx = ((T.x + T.z)*0.5f - pr.x) / (0.1f*pr.z);
    const float gcy = ((T.y + T.w)*0.5f - pr.y) / (0.1f*pr.w);
    const float gw  = __logf((T.z - T.x) / pr.z) * 5.0f;
    const float gh  = __logf((T.w - T.y) / pr.w) * 5.0f;
    const float4 ld = ((const float4* __restrict__)loc)[r];
    float d, ad;
    d = ld.x - gcx; ad = fabsf(d); ll += (ad < 1.0f) ? 0.5f*d*d : ad - 0.5f;
    d = ld.y - gcy; ad = fabsf(d); ll += (ad < 1.0f) ? 0.5f*d*d : ad - 0.5f;
    d = ld.z - gw;  ad = fabsf(d); ll += (ad < 1.0f) ? 0.5f*d*d : ad - 0.5f;
    d = ld.w - gh;  ad = fabsf(d); ll += (ad < 1.0f) ? 0.5f*d*d : ad - 0.5f;
  }

  // wave -> block reduction, 3 atomics per block total
  #pragma unroll
  for (int off = 32; off > 0; off >>= 1){
    cp += __shfl_down(cp, off);
    ll += __shfl_down(ll, off);
    pc += __shfl_down(pc, off);
  }
  __shared__ float rcp[4], rll[4];
  __shared__ int rpc[4];
  const int wv = tid >> 6;
  if ((tid & 63) == 0){ rcp[wv] = cp; rll[wv] = ll; rpc[wv] = pc; }
  __syncthreads();
  if (tid == 0){
    atomicAdd(&ce_pos[b], (rcp[0]+rcp[1])+(rcp[2]+rcp[3]));
    atomicAdd(&loss_l[b], (rll[0]+rll[1])+(rll[2]+rll[3]));
    atomicAdd(&num_pos[b], (rpc[0]+rpc[1])+(rpc[2]+rpc[3]));
  }
}

// ---------------------------------------------------------------------------
// Kernel D: exact top-k sum per image via 4-pass radix select on float bits.
// 1024 threads; NP = 6141 float4 exactly; single-wave suffix scan (3 syncs
// per pass instead of 16).
// ---------------------------------------------------------------------------
__global__ __launch_bounds__(1024) void k_topk(
    const float* __restrict__ mine, const int* __restrict__ num_pos,
    float* __restrict__ topk)
{
  const int b = blockIdx.x;
  const int tid = threadIdx.x;
  const float4* __restrict__ d4 =
      (const float4* __restrict__)(mine + (size_t)b * NP);   // 6141 float4
  const int k = min(3 * num_pos[b], NP - 1);

  __shared__ unsigned hist[256];
  __shared__ unsigned s_prefix;
  __shared__ int s_rem;
  __shared__ float wsum[16];

  if (k <= 0){
    if (tid == 0) topk[b] = 0.0f;
    return;
  }
  if (tid == 0){ s_prefix = 0u; s_rem = k; }

  for (int pass = 0; pass < 4; ++pass){
    const int shift = 24 - pass*8;
    if (tid < 256) hist[tid] = 0u;
    __syncthreads();                          // (A) hist zeroed, sel stable
    const unsigned pref = s_prefix;
    const int rem = s_rem;
    for (int i = tid; i < 6141; i += 1024){
      const float4 v = d4[i];
      unsigned u;
      u = __float_as_uint(v.x);
      if (pass == 0 || (u >> (shift+8)) == pref) atomicAdd(&hist[(u>>shift)&255u], 1u);
      u = __float_as_uint(v.y);
      if (pass == 0 || (u >> (shift+8)) == pref) atomicAdd(&hist[(u>>shift)&255u], 1u);
      u = __float_as_uint(v.z);
      if (pass == 0 || (u >> (shift+8)) == pref) atomicAdd(&hist[(u>>shift)&255u], 1u);
      u = __float_as_uint(v.w);
      if (pass == 0 || (u >> (shift+8)) == pref) atomicAdd(&hist[(u>>shift)&255u], 1u);
    }
    __syncthreads();                          // (B) hist complete
    if (tid < 64){
      const unsigned h0 = hist[4*tid], h1 = hist[4*tid+1];
      const unsigned h2 = hist[4*tid+2], h3 = hist[4*tid+3];
      const unsigned pl = h0 + h1 + h2 + h3;
      unsigned S = pl;                        // inclusive suffix over lanes
      #pragma unroll
      for (int off = 1; off < 64; off <<= 1){
        const unsigned v = __shfl_down(S, off);
        if (tid + off < 64) S += v;
      }
      const unsigned Sn = S - pl;             // suffix starting at bin 4*tid+4
      const unsigned t3 = h3 + Sn;
      const unsigned t2 = h2 + t3;
      const unsigned t1 = h1 + t2;
      const unsigned t0 = h0 + t1;
      if ((int)t0 >= rem && (int)t1 < rem){ s_prefix = (pref<<8) | (4u*tid+0u); s_rem = rem - (int)t1; }
      if ((int)t1 >= rem && (int)t2 < rem){ s_prefix = (pref<<8) | (4u*tid+1u); s_rem = rem - (int)t2; }
      if ((int)t2 >= rem && (int)t3 < rem){ s_prefix = (pref<<8) | (4u*tid+2u); s_rem = rem - (int)t3; }
      if ((int)t3 >= rem && (int)Sn < rem){ s_prefix = (pref<<8) | (4u*tid+3u); s_rem = rem - (int)Sn; }
    }
    __syncthreads();                          // (C) selection visible
  }

  const unsigned kb = s_prefix;
  const int rem = s_rem;
  const float kv = __uint_as_float(kb);
  float acc = 0.0f;
  for (int i = tid; i < 6141; i += 1024){
    const float4 v = d4[i];
    if (__float_as_uint(v.x) > kb) acc += v.x;
    if (__float_as_uint(v.y) > kb) acc += v.y;
    if (__float_as_uint(v.z) > kb) acc += v.z;
    if (__float_as_uint(v.w) > kb) acc += v.w;
  }
  #pragma unroll
  for (int off = 32; off > 0; off >>= 1) acc += __shfl_down(acc, off);
  if ((tid & 63) == 0) wsum[tid >> 6] = acc;
  __syncthreads();
  if (tid == 0){
    float s = 0.0f;
    #pragma unroll
    for (int j = 0; j < 16; ++j) s += wsum[j];
    topk[b] = s + (float)rem * kv;
  }
}

// ---------------------------------------------------------------------------
// Kernel E: final combine
// ---------------------------------------------------------------------------
__global__ void k_final(const int* __restrict__ num_pos,
                        const float* __restrict__ loss_l,
                        const float* __restrict__ ce_pos,
                        const float* __restrict__ topk,
                        float* __restrict__ out)
{
  const int tid = threadIdx.x;
  int   np = num_pos[tid];
  float ll = loss_l[tid];
  float cp = ce_pos[tid];
  float tk = topk[tid];
  #pragma unroll
  for (int off = 32; off > 0; off >>= 1){
    np += __shfl_down(np, off);
    ll += __shfl_down(ll, off);
    cp += __shfl_down(cp, off);
    tk += __shfl_down(tk, off);
  }
  if (tid == 0){
    const float n = (float)max(np, 1);
    out[0] = ll / n;
    out[1] = (cp + tk) / n;
  }
}

// ---------------------------------------------------------------------------
extern "C" void kernel_launch(void* const* d_in, const int* in_sizes, int n_in,
                              void* d_out, int out_size, void* d_ws, size_t ws_size,
                              hipStream_t stream)
{
  const float* loc     = (const float*)d_in[0];
  const float* conf    = (const float*)d_in[1];
  const float* priors  = (const float*)d_in[2];
  const float* tboxes  = (const float*)d_in[3];
  const int*   tlabels = (const int*)d_in[4];
  float* out = (float*)d_out;

  char* ws = (char*)d_ws;
  int*   num_pos = (int*)(ws + 0);        // 64
  float* loss_l  = (float*)(ws + 256);    // 64
  float* ce_pos  = (float*)(ws + 512);    // 64
  float* topk    = (float*)(ws + 768);    // 64
  unsigned long long* bpk = (unsigned long long*)(ws + 1024);  // 64*50*8
  float* mine = (float*)(ws + 26624);     // NROWS floats, 16B aligned

  hipMemsetAsync(ws, 0, 26624, stream);

  dim3 gA(NB, NT/TCH, NSEG);
  k_bestprior<<<gA, 256, 0, stream>>>(priors, tboxes, bpk);

  dim3 gC((NP + RPB - 1)/RPB, NB);
  k_ce<<<gC, 256, 0, stream>>>(conf, loc, priors, tboxes, tlabels,
                               bpk, mine, ce_pos, loss_l, num_pos);

  k_topk<<<NB, 1024, 0, stream>>>(mine, num_pos, topk);

  k_final<<<1, 64, 0, stream>>>(num_pos, loss_l, ce_pos, topk, out);
}

// Round 4
// 865.190 us; speedup vs baseline: 1.1587x; 1.1300x over previous
//
#include <hip/hip_runtime.h>
#include <cstdint>
#include <cstddef>

#define NB 64
#define NP 24564
#define NC 81
#define NROWS (NB*NP)   // 1,572,096
#define NT 50
#define TCH 10          // truths per block in best-prior kernel
#define NSEG 16         // P-segments in best-prior kernel
#define SEGLEN 1536     // 16*1536 = 24576 >= NP
#define RPB 64          // rows per k_ce block (4 threads/row, 256 threads)

__device__ __forceinline__ unsigned long long umax64(unsigned long long a, unsigned long long b){
  return a > b ? a : b;
}

// ---------------------------------------------------------------------------
// Kernel A: per (b,t) best prior (argmax over P), P split into NSEG segments.
// packed u64 key = (iou_bits<<32) | ~p  -> max = (max iou, then smallest p).
// Wave shuffle reduce -> 4 partials in LDS -> global atomicMax into bpk.
// ---------------------------------------------------------------------------
__global__ __launch_bounds__(256) void k_bestprior(
    const float* __restrict__ priors, const float* __restrict__ tboxes,
    unsigned long long* __restrict__ bpk)
{
  __shared__ float tb[TCH*4];
  __shared__ float ta[TCH];
  __shared__ unsigned long long part[4][TCH];
  const int tid = threadIdx.x;
  const int b  = blockIdx.x;
  const int t0 = blockIdx.y * TCH;
  const int i0 = blockIdx.z * SEGLEN;
  const int iend = min(i0 + SEGLEN, NP);
  if (tid < TCH*4) tb[tid] = tboxes[(b*NT + t0)*4 + tid];
  __syncthreads();
  if (tid < TCH) ta[tid] = (tb[tid*4+2]-tb[tid*4+0]) * (tb[tid*4+3]-tb[tid*4+1]);
  __syncthreads();

  unsigned long long best[TCH];
  #pragma unroll
  for (int j = 0; j < TCH; ++j) best[j] = 0ULL;

  for (int i = i0 + tid; i < iend; i += 256){
    const float4 pr = ((const float4* __restrict__)priors)[i];
    const float px1 = pr.x - 0.5f*pr.z, py1 = pr.y - 0.5f*pr.w;
    const float px2 = pr.x + 0.5f*pr.z, py2 = pr.y + 0.5f*pr.w;
    const float pa  = pr.z * pr.w;
    const unsigned long long low = (unsigned long long)(~(unsigned)i);
    #pragma unroll
    for (int j = 0; j < TCH; ++j){
      float ix = fminf(tb[j*4+2], px2) - fmaxf(tb[j*4+0], px1);
      float iy = fminf(tb[j*4+3], py2) - fmaxf(tb[j*4+1], py1);
      ix = fmaxf(ix, 0.0f); iy = fmaxf(iy, 0.0f);
      const float inter = ix * iy;
      const float iou = inter / (ta[j] + pa - inter);
      const unsigned long long key =
          ((unsigned long long)__float_as_uint(iou) << 32) | low;
      best[j] = umax64(best[j], key);
    }
  }
  // wave-level reduce (64 lanes)
  #pragma unroll
  for (int off = 32; off > 0; off >>= 1){
    #pragma unroll
    for (int j = 0; j < TCH; ++j)
      best[j] = umax64(best[j], __shfl_down(best[j], off));
  }
  const int wv = tid >> 6;
  if ((tid & 63) == 0){
    #pragma unroll
    for (int j = 0; j < TCH; ++j) part[wv][j] = best[j];
  }
  __syncthreads();
  if (tid < TCH){
    const unsigned long long m =
        umax64(umax64(part[0][tid], part[1][tid]),
               umax64(part[2][tid], part[3][tid]));
    atomicMax(&bpk[b*NT + t0 + tid], m);
  }
}

// ---------------------------------------------------------------------------
// Kernel B: fused matching + CE + positive loc loss + counts.
// R4 fix (counter-driven): R2/R3's WRITE_SIZE=506MB was the st[6] staging
// array living in SCRATCH (VGPR=36, 80B/thread of HBM writebacks). Replace
// the global->reg->LDS staging with __builtin_amdgcn_global_load_lds
// width=16: direct HBM->LDS, zero VGPR round trip, loads in flight until
// the vmcnt(0) drain at __syncthreads. LDS dest is wave-uniform base +
// lane*16 (m104): our layout is linear in lane order, tail guard masks a
// lane SUFFIX only, so the pattern holds.
// 4 threads/row: matching split 13 truths/thread (packed u64 shfl_xor
// reduce); softmax = two LDS passes (no per-thread arrays -> no scratch).
// ---------------------------------------------------------------------------
__global__ __launch_bounds__(256) void k_ce(
    const float* __restrict__ conf, const float* __restrict__ loc,
    const float* __restrict__ priors, const float* __restrict__ tboxes,
    const int* __restrict__ tlabels,
    const unsigned long long* __restrict__ bpk,
    float* __restrict__ mine, float* __restrict__ ce_pos,
    float* __restrict__ loss_l, int* __restrict__ num_pos)
{
  __shared__ float4 cbuf4[(RPB*NC)/4 + 1];   // 1296 float4 + guard = 20,752 B
  __shared__ float4 tb4[NT];
  __shared__ float ta[NT];
  __shared__ int ips[NT];
  __shared__ int tl[NT];
  float* cbuf = (float*)cbuf4;

  const int tid = threadIdx.x;
  const int b  = blockIdx.y;
  const int p0 = blockIdx.x * RPB;
  const int rows = min(RPB, NP - p0);

  // --- stage conf tile: direct global->LDS, no VGPR/scratch round trip ---
  const float4* __restrict__ csrc =
      (const float4* __restrict__)(conf + (size_t)(b*NP + p0) * NC);
  const int nf4 = (rows * NC) >> 2;          // rows%4==0 always -> exact
  const int wbase = tid & ~63;               // wave-uniform lane-0 slot
  #pragma unroll
  for (int j = 0; j < 6; ++j){
    const int i = tid + j*256;
    if (i < nf4){
      __builtin_amdgcn_global_load_lds(
          (const __attribute__((address_space(1))) void*)(csrc + i),
          (__attribute__((address_space(3))) void*)(cbuf4 + (j*256 + wbase)),
          16, 0, 0);
    }
  }

  // --- truth metadata in parallel with the staging loads ---
  if (tid < NT*4){
    ((float*)tb4)[tid] = tboxes[b*NT*4 + tid];
  } else if (tid < NT*4 + NT){
    const int t = tid - NT*4;
    const float4 T = ((const float4* __restrict__)tboxes)[b*NT + t];
    ta[t] = (T.z - T.x) * (T.w - T.y);
    tl[t] = tlabels[b*NT + t];
    ips[t] = (int)(~(unsigned)(bpk[b*NT + t] & 0xffffffffULL));
  }
  __syncthreads();   // compiler drains vmcnt(0): staged tile complete

  const int row = tid >> 2;        // 0..63
  const int q   = tid & 3;         // quarter of the row
  const bool active = row < rows;
  const int p = p0 + (active ? row : 0);
  const int r = b*NP + p;

  // --- matching: 50 truths split across the quad (t = q, q+4, ...) ---
  const float4 pr = ((const float4* __restrict__)priors)[p];
  const float px1 = pr.x - 0.5f*pr.z, py1 = pr.y - 0.5f*pr.w;
  const float px2 = pr.x + 0.5f*pr.z, py2 = pr.y + 0.5f*pr.w;
  const float pa  = pr.z * pr.w;
  unsigned long long bk = 0ULL;
  int mo = -1;                      // override candidate (max t wins)
  {
    int t = q;
    #pragma unroll
    for (int k = 0; k < 13; ++k){
      if (t < NT){
        const float4 T = tb4[t];               // broadcast ds_read_b128
        float ix = fminf(T.z, px2) - fmaxf(T.x, px1);
        float iy = fminf(T.w, py2) - fmaxf(T.y, py1);
        ix = fmaxf(ix, 0.0f); iy = fmaxf(iy, 0.0f);
        const float inter = ix * iy;
        const float iou = inter / (ta[t] + pa - inter);   // iou >= 0
        const unsigned long long key =
            ((unsigned long long)__float_as_uint(iou) << 32)
            | (unsigned long long)(~(unsigned)t);
        bk = umax64(bk, key);
        if (ips[t] == p) mo = t;    // ascending within thread -> max kept
      }
      t += 4;
    }
  }
  bk = umax64(bk, __shfl_xor(bk, 1));
  bk = umax64(bk, __shfl_xor(bk, 2));
  mo = max(mo, __shfl_xor(mo, 1));
  mo = max(mo, __shfl_xor(mo, 2));
  int   ti = (int)(~(unsigned)(bk & 0xffffffffULL));
  float ov = __uint_as_float((unsigned)(bk >> 32));
  if (mo >= 0){ ov = 2.0f; ti = mo; }
  const int cls = (ov < 0.5f) ? 0 : (tl[ti] + 1);

  // --- softmax CE: two LDS passes over the quarter (no register array) ---
  // q covers cols [20q, 20q+20); q==3 additionally col 80.
  const float* __restrict__ myrow = cbuf + row * NC;
  const int c0 = 20 * q;
  const float x20 = (q == 3) ? myrow[80] : -INFINITY;

  float mh = myrow[c0];
  #pragma unroll
  for (int c = 1; c < 20; ++c) mh = fmaxf(mh, myrow[c0 + c]);
  mh = fmaxf(mh, x20);
  float m = fmaxf(mh, __shfl_xor(mh, 1));
  m = fmaxf(m, __shfl_xor(m, 2));

  float sh = 0.0f;
  #pragma unroll
  for (int c = 0; c < 20; ++c) sh += __expf(myrow[c0 + c] - m);
  sh += __expf(x20 - m);            // exp(-inf)=0 for q!=3
  float S = sh + __shfl_xor(sh, 1);
  S += __shfl_xor(S, 2);

  const float lg = myrow[cls];      // broadcast within the quad
  const float ce = m + __logf(S) - lg;

  const bool own = active && (q == 0);
  const bool pos = own && (cls > 0);
  if (own) mine[r] = pos ? 0.0f : ce;

  float cp = pos ? ce : 0.0f;
  float ll = 0.0f;
  int   pc = pos ? 1 : 0;
  if (pos){
    const float4 T = tb4[ti];
    const float gcx = ((T.x + T.z)*0.5f - pr.x) / (0.1f*pr.z);
    const float gcy = ((T.y + T.w)*0.5f - pr.y) / (0.1f*pr.w);
    const float gw  = __logf((T.z - T.x) / pr.z) * 5.0f;
    const float gh  = __logf((T.w - T.y) / pr.w) * 5.0f;
    const float4 ld = ((const float4* __restrict__)loc)[r];
    float d, ad;
    d = ld.x - gcx; ad = fabsf(d); ll += (ad < 1.0f) ? 0.5f*d*d : ad - 0.5f;
    d = ld.y - gcy; ad = fabsf(d); ll += (ad < 1.0f) ? 0.5f*d*d : ad - 0.5f;
    d = ld.z - gw;  ad = fabsf(d); ll += (ad < 1.0f) ? 0.5f*d*d : ad - 0.5f;
    d = ld.w - gh;  ad = fabsf(d); ll += (ad < 1.0f) ? 0.5f*d*d : ad - 0.5f;
  }

  // wave -> block reduction, 3 atomics per block total
  #pragma unroll
  for (int off = 32; off > 0; off >>= 1){
    cp += __shfl_down(cp, off);
    ll += __shfl_down(ll, off);
    pc += __shfl_down(pc, off);
  }
  __shared__ float rcp[4], rll[4];
  __shared__ int rpc[4];
  const int wv = tid >> 6;
  if ((tid & 63) == 0){ rcp[wv] = cp; rll[wv] = ll; rpc[wv] = pc; }
  __syncthreads();
  if (tid == 0){
    atomicAdd(&ce_pos[b], (rcp[0]+rcp[1])+(rcp[2]+rcp[3]));
    atomicAdd(&loss_l[b], (rll[0]+rll[1])+(rll[2]+rll[3]));
    atomicAdd(&num_pos[b], (rpc[0]+rpc[1])+(rpc[2]+rpc[3]));
  }
}

// ---------------------------------------------------------------------------
// Kernel D: exact top-k sum per image via 4-pass radix select on float bits.
// 1024 threads; NP = 6141 float4 exactly; single-wave suffix scan (3 syncs
// per pass instead of 16).
// ---------------------------------------------------------------------------
__global__ __launch_bounds__(1024) void k_topk(
    const float* __restrict__ mine, const int* __restrict__ num_pos,
    float* __restrict__ topk)
{
  const int b = blockIdx.x;
  const int tid = threadIdx.x;
  const float4* __restrict__ d4 =
      (const float4* __restrict__)(mine + (size_t)b * NP);   // 6141 float4
  const int k = min(3 * num_pos[b], NP - 1);

  __shared__ unsigned hist[256];
  __shared__ unsigned s_prefix;
  __shared__ int s_rem;
  __shared__ float wsum[16];

  if (k <= 0){
    if (tid == 0) topk[b] = 0.0f;
    return;
  }
  if (tid == 0){ s_prefix = 0u; s_rem = k; }

  for (int pass = 0; pass < 4; ++pass){
    const int shift = 24 - pass*8;
    if (tid < 256) hist[tid] = 0u;
    __syncthreads();                          // (A) hist zeroed, sel stable
    const unsigned pref = s_prefix;
    const int rem = s_rem;
    for (int i = tid; i < 6141; i += 1024){
      const float4 v = d4[i];
      unsigned u;
      u = __float_as_uint(v.x);
      if (pass == 0 || (u >> (shift+8)) == pref) atomicAdd(&hist[(u>>shift)&255u], 1u);
      u = __float_as_uint(v.y);
      if (pass == 0 || (u >> (shift+8)) == pref) atomicAdd(&hist[(u>>shift)&255u], 1u);
      u = __float_as_uint(v.z);
      if (pass == 0 || (u >> (shift+8)) == pref) atomicAdd(&hist[(u>>shift)&255u], 1u);
      u = __float_as_uint(v.w);
      if (pass == 0 || (u >> (shift+8)) == pref) atomicAdd(&hist[(u>>shift)&255u], 1u);
    }
    __syncthreads();                          // (B) hist complete
    if (tid < 64){
      const unsigned h0 = hist[4*tid], h1 = hist[4*tid+1];
      const unsigned h2 = hist[4*tid+2], h3 = hist[4*tid+3];
      const unsigned pl = h0 + h1 + h2 + h3;
      unsigned S = pl;                        // inclusive suffix over lanes
      #pragma unroll
      for (int off = 1; off < 64; off <<= 1){
        const unsigned v = __shfl_down(S, off);
        if (tid + off < 64) S += v;
      }
      const unsigned Sn = S - pl;             // suffix starting at bin 4*tid+4
      const unsigned t3 = h3 + Sn;
      const unsigned t2 = h2 + t3;
      const unsigned t1 = h1 + t2;
      const unsigned t0 = h0 + t1;
      if ((int)t0 >= rem && (int)t1 < rem){ s_prefix = (pref<<8) | (4u*tid+0u); s_rem = rem - (int)t1; }
      if ((int)t1 >= rem && (int)t2 < rem){ s_prefix = (pref<<8) | (4u*tid+1u); s_rem = rem - (int)t2; }
      if ((int)t2 >= rem && (int)t3 < rem){ s_prefix = (pref<<8) | (4u*tid+2u); s_rem = rem - (int)t3; }
      if ((int)t3 >= rem && (int)Sn < rem){ s_prefix = (pref<<8) | (4u*tid+3u); s_rem = rem - (int)Sn; }
    }
    __syncthreads();                          // (C) selection visible
  }

  const unsigned kb = s_prefix;
  const int rem = s_rem;
  const float kv = __uint_as_float(kb);
  float acc = 0.0f;
  for (int i = tid; i < 6141; i += 1024){
    const float4 v = d4[i];
    if (__float_as_uint(v.x) > kb) acc += v.x;
    if (__float_as_uint(v.y) > kb) acc += v.y;
    if (__float_as_uint(v.z) > kb) acc += v.z;
    if (__float_as_uint(v.w) > kb) acc += v.w;
  }
  #pragma unroll
  for (int off = 32; off > 0; off >>= 1) acc += __shfl_down(acc, off);
  if ((tid & 63) == 0) wsum[tid >> 6] = acc;
  __syncthreads();
  if (tid == 0){
    float s = 0.0f;
    #pragma unroll
    for (int j = 0; j < 16; ++j) s += wsum[j];
    topk[b] = s + (float)rem * kv;
  }
}

// ---------------------------------------------------------------------------
// Kernel E: final combine
// ---------------------------------------------------------------------------
__global__ void k_final(const int* __restrict__ num_pos,
                        const float* __restrict__ loss_l,
                        const float* __restrict__ ce_pos,
                        const float* __restrict__ topk,
                        float* __restrict__ out)
{
  const int tid = threadIdx.x;
  int   np = num_pos[tid];
  float ll = loss_l[tid];
  float cp = ce_pos[tid];
  float tk = topk[tid];
  #pragma unroll
  for (int off = 32; off > 0; off >>= 1){
    np += __shfl_down(np, off);
    ll += __shfl_down(ll, off);
    cp += __shfl_down(cp, off);
    tk += __shfl_down(tk, off);
  }
  if (tid == 0){
    const float n = (float)max(np, 1);
    out[0] = ll / n;
    out[1] = (cp + tk) / n;
  }
}

// ---------------------------------------------------------------------------
extern "C" void kernel_launch(void* const* d_in, const int* in_sizes, int n_in,
                              void* d_out, int out_size, void* d_ws, size_t ws_size,
                              hipStream_t stream)
{
  const float* loc     = (const float*)d_in[0];
  const float* conf    = (const float*)d_in[1];
  const float* priors  = (const float*)d_in[2];
  const float* tboxes  = (const float*)d_in[3];
  const int*   tlabels = (const int*)d_in[4];
  float* out = (float*)d_out;

  char* ws = (char*)d_ws;
  int*   num_pos = (int*)(ws + 0);        // 64
  float* loss_l  = (float*)(ws + 256);    // 64
  float* ce_pos  = (float*)(ws + 512);    // 64
  float* topk    = (float*)(ws + 768);    // 64
  unsigned long long* bpk = (unsigned long long*)(ws + 1024);  // 64*50*8
  float* mine = (float*)(ws + 26624);     // NROWS floats, 16B aligned

  hipMemsetAsync(ws, 0, 26624, stream);

  dim3 gA(NB, NT/TCH, NSEG);
  k_bestprior<<<gA, 256, 0, stream>>>(priors, tboxes, bpk);

  dim3 gC((NP + RPB - 1)/RPB, NB);
  k_ce<<<gC, 256, 0, stream>>>(conf, loc, priors, tboxes, tlabels,
                               bpk, mine, ce_pos, loss_l, num_pos);

  k_topk<<<NB, 1024, 0, stream>>>(mine, num_pos, topk);

  k_final<<<1, 64, 0, stream>>>(num_pos, loss_l, ce_pos, topk, out);
}